// Round 5
// baseline (1253.149 us; speedup 1.0000x reference)
//
#include <hip/hip_runtime.h>

#define DIM 64
#define EPS 1e-8f

// ---------------------------------------------------------------------------
// Pipeline (CSR, no float atomics, no h materialization):
//   scan1/2/3 : exclusive scan of degree -> off[] (+cursor copy)
//   sort      : counting sort -> csr cols grouped by row (1 int atomic/edge)
//   gather    : z[i] = deg_i*x[i] + sum x[csr[j]]   -> written to d_out
//               (float4 lanes, 4 edges/wave-step, zero LDS, 8 waves/SIMD)
//   out       : agg = z@fc_w^T + 2*deg*fc_b ; alpha/beta/gamma from x;
//               out = (relu(b)*agg + g)/(relu(a) + relu(b)*deg + EPS)
//
// Algebra: agg[i] = k_i*h[i] + sum h[col] with h = x@W^T + b and k_i ==
// degree[i] (degree IS the out-degree), so
//   agg[i] = (k_i*x[i] + sum x[col])@W^T + 2*k_i*b = z[i]@W^T + 2*deg_i*b.
// The gather runs on raw x (no dependency on any compute kernel), and the
// FC transform collapses into the epilogue's 4-way interleaved matvec tile.
// ---------------------------------------------------------------------------

__global__ __launch_bounds__(256) void scan1_kernel(
    const float* __restrict__ degree, int* __restrict__ off,
    int* __restrict__ bsum, int n)
{
  __shared__ int s[256];
  const int t = threadIdx.x;
  const int i = blockIdx.x * 256 + t;
  const int v = (i < n) ? (int)(degree[i] + 0.5f) : 0;
  s[t] = v;
  __syncthreads();
  for (int st = 1; st < 256; st <<= 1) {
    int a = (t >= st) ? s[t - st] : 0;
    __syncthreads();
    s[t] += a;
    __syncthreads();
  }
  if (i < n) off[i] = s[t] - v;
  if (t == 255) bsum[blockIdx.x] = s[t];
}

__global__ __launch_bounds__(512) void scan2_kernel(
    const int* __restrict__ bsum, int* __restrict__ bpre,
    int* __restrict__ off, int nb, int ch, int n)
{
  __shared__ int s[512];
  const int t = threadIdx.x;
  const int base = t * ch;
  int local = 0;
  for (int q = 0; q < ch; ++q) {
    const int j = base + q;
    if (j < nb) local += bsum[j];
  }
  s[t] = local;
  __syncthreads();
  for (int st = 1; st < 512; st <<= 1) {
    int a = (t >= st) ? s[t - st] : 0;
    __syncthreads();
    s[t] += a;
    __syncthreads();
  }
  int run = s[t] - local;
  for (int q = 0; q < ch; ++q) {
    const int j = base + q;
    if (j < nb) { bpre[j] = run; run += bsum[j]; }
  }
  if (t == 511) off[n] = s[511];
}

__global__ __launch_bounds__(256) void scan3_kernel(
    int* __restrict__ off, int* __restrict__ cur,
    const int* __restrict__ bpre, int n)
{
  const int i = blockIdx.x * 256 + threadIdx.x;
  if (i < n) {
    const int o = off[i] + bpre[blockIdx.x];
    off[i] = o;
    cur[i] = o;
  }
}

__global__ __launch_bounds__(256) void sort_kernel(
    const int* __restrict__ ei, int* __restrict__ cur,
    int* __restrict__ csr, int E)
{
  const int tid = blockIdx.x * 256 + threadIdx.x;
  const int stride = gridDim.x * 256;
  for (int e = tid; e < E; e += stride) {
    const int r = ei[e];
    const int c = ei[E + e];
    const int p = atomicAdd(&cur[r], 1);
    csr[p] = c;
  }
}

// z[i] = deg_i*x[i] + sum_j x[csr[j]]  — float4 lanes, 4 edges per wave-step.
// sub = lane>>4 selects edge slot; l16 = lane&15 covers the 64-dim row as
// float4. One wave-step gathers 4 full 256B x-rows; unroll x2 = 8 edges in
// flight. Zero LDS + low VGPR -> 8 waves/SIMD for latency hiding.
__global__ __launch_bounds__(256, 8) void gather_kernel(
    const float* __restrict__ x, const int* __restrict__ off,
    const int* __restrict__ csr, const float* __restrict__ degree,
    float* __restrict__ z, int n)
{
  const int lane = threadIdx.x & 63;
  const int sub = lane >> 4;
  const int l16 = lane & 15;
  const int wid = (blockIdx.x << 2) + (threadIdx.x >> 6);
  const int nwaves = gridDim.x << 2;
  for (int node = wid; node < n; node += nwaves) {
    float4 acc = make_float4(0.f, 0.f, 0.f, 0.f);
    if (sub == 0) {                 // fold deg*x[i] (row term) once
      const float4 xv = *(const float4*)&x[((size_t)node << 6) + (l16 << 2)];
      const float d = degree[node];
      acc.x = d * xv.x; acc.y = d * xv.y; acc.z = d * xv.z; acc.w = d * xv.w;
    }
    const int o0 = off[node];
    const int o1 = off[node + 1];
    int j = o0;
    for (; j + 8 <= o1; j += 8) {   // 8 edges per iter, 2 indep float4 loads
      const int c0 = csr[j + sub];
      const int c1 = csr[j + 4 + sub];
      const float4 v0 = *(const float4*)&x[((size_t)c0 << 6) + (l16 << 2)];
      const float4 v1 = *(const float4*)&x[((size_t)c1 << 6) + (l16 << 2)];
      acc.x += v0.x + v1.x; acc.y += v0.y + v1.y;
      acc.z += v0.z + v1.z; acc.w += v0.w + v1.w;
    }
    if (j + 4 <= o1) {
      const int c = csr[j + sub];
      const float4 v = *(const float4*)&x[((size_t)c << 6) + (l16 << 2)];
      acc.x += v.x; acc.y += v.y; acc.z += v.z; acc.w += v.w;
      j += 4;
    }
    const int rem = o1 - j;         // 0..3 tail edges
    if (sub < rem) {
      const int c = csr[j + sub];
      const float4 v = *(const float4*)&x[((size_t)c << 6) + (l16 << 2)];
      acc.x += v.x; acc.y += v.y; acc.z += v.z; acc.w += v.w;
    }
    acc.x += __shfl_xor(acc.x, 16, 64); acc.y += __shfl_xor(acc.y, 16, 64);
    acc.z += __shfl_xor(acc.z, 16, 64); acc.w += __shfl_xor(acc.w, 16, 64);
    acc.x += __shfl_xor(acc.x, 32, 64); acc.y += __shfl_xor(acc.y, 32, 64);
    acc.z += __shfl_xor(acc.z, 32, 64); acc.w += __shfl_xor(acc.w, 32, 64);
    if (sub == 0) {
      *(float4*)&z[((size_t)node << 6) + (l16 << 2)] = acc;
    }
  }
}

// Fused epilogue: 4 matvecs per node with one interleaved LDS tile.
// w_lds[k][(d^k)*4] = {fc, dir, neu, rob} -> one ds_read_b128 feeds 4 FMAs.
// agg = z@fc_w^T + 2*deg*fc_b; a/b/g from x; z lives in d_out (in-place).
__global__ __launch_bounds__(512, 4) void out_kernel(
    const float* __restrict__ x,
    const float* __restrict__ fc_w,  const float* __restrict__ fc_b,
    const float* __restrict__ dir_w, const float* __restrict__ dir_b,
    const float* __restrict__ neu_w, const float* __restrict__ neu_b,
    const float* __restrict__ rob_w, const float* __restrict__ rob_b,
    const float* __restrict__ degree, float* __restrict__ out, int n)
{
  __shared__ float w_lds[DIM * DIM * 4];
  __shared__ float b_lds[4 * DIM];
  const int t = threadIdx.x;
  for (int i = t; i < DIM * DIM; i += 512) {
    const int d = i >> 6, k = i & 63;
    const int s = (k << 8) | ((d ^ k) << 2);
    w_lds[s + 0] = fc_w[i];
    w_lds[s + 1] = dir_w[i];
    w_lds[s + 2] = neu_w[i];
    w_lds[s + 3] = rob_w[i];
  }
  if (t < DIM) {
    b_lds[t]       = fc_b[t];
    b_lds[64 + t]  = dir_b[t];
    b_lds[128 + t] = neu_b[t];
    b_lds[192 + t] = rob_b[t];
  }
  __syncthreads();

  const int lane = t & 63;
  const int wid = (blockIdx.x << 3) + (t >> 6);
  const int nwaves = gridDim.x << 3;
  for (int node = wid; node < n; node += nwaves) {
    const size_t rowo = ((size_t)node << 6) | lane;
    const float xv = x[rowo];
    const float zv = out[rowo];          // z written by gather_kernel
    const float deg = degree[node];
    float agg = 2.f * deg * b_lds[lane];
    float a = b_lds[64 + lane];
    float b = b_lds[128 + lane];
    float g = b_lds[192 + lane];
#pragma unroll
    for (int k = 0; k < DIM; ++k) {
      const float xk = __shfl(xv, k, 64);
      const float zk = __shfl(zv, k, 64);
      const float4 w = *(const float4*)&w_lds[(k << 8) | ((lane ^ k) << 2)];
      agg = fmaf(zk, w.x, agg);
      a = fmaf(xk, w.y, a);
      b = fmaf(xk, w.z, b);
      g = fmaf(xk, w.w, g);
    }
    a = fmaxf(a, 0.f);
    b = fmaxf(b, 0.f);
    out[rowo] = fmaf(b, agg, g) / (fmaf(b, deg, a) + EPS);
  }
}

extern "C" void kernel_launch(void* const* d_in, const int* in_sizes, int n_in,
                              void* d_out, int out_size, void* d_ws, size_t ws_size,
                              hipStream_t stream) {
  const float* x      = (const float*)d_in[0];
  const int*   ei     = (const int*)  d_in[1];
  const float* degree = (const float*)d_in[2];
  const float* fc_w   = (const float*)d_in[3];
  const float* fc_b   = (const float*)d_in[4];
  const float* dir_w  = (const float*)d_in[5];
  const float* dir_b  = (const float*)d_in[6];
  const float* neu_w  = (const float*)d_in[7];
  const float* neu_b  = (const float*)d_in[8];
  const float* rob_w  = (const float*)d_in[9];
  const float* rob_b  = (const float*)d_in[10];
  float* out = (float*)d_out;

  const int n = in_sizes[0] / DIM;
  const int E = in_sizes[1] / 2;
  const int NB = (n + 255) / 256;
  const int CH = (NB + 511) / 512;

  // ws layout: csr | off | cur | bsum | bpre  (~7.8 MB @ E=1.6M, N=100k)
  // z lives in d_out (gather writes it; out_kernel updates in place).
  int* csr  = (int*)d_ws;
  int* off  = csr + E;
  int* cur  = off + (n + 1);
  int* bsum = cur + n;
  int* bpre = bsum + NB;

  hipLaunchKernelGGL(scan1_kernel, dim3(NB), dim3(256), 0, stream,
                     degree, off, bsum, n);
  hipLaunchKernelGGL(scan2_kernel, dim3(1), dim3(512), 0, stream,
                     bsum, bpre, off, NB, CH, n);
  hipLaunchKernelGGL(scan3_kernel, dim3(NB), dim3(256), 0, stream,
                     off, cur, bpre, n);
  hipLaunchKernelGGL(sort_kernel, dim3(4096), dim3(256), 0, stream,
                     ei, cur, csr, E);
  hipLaunchKernelGGL(gather_kernel, dim3(2048), dim3(256), 0, stream,
                     x, off, csr, degree, out, n);
  hipLaunchKernelGGL(out_kernel, dim3(512), dim3(512), 0, stream,
                     x, fc_w, fc_b, dir_w, dir_b, neu_w, neu_b, rob_w, rob_b,
                     degree, out, n);
}